// Round 1
// 354.615 us; speedup vs baseline: 1.0166x; 1.0166x over previous
//
#include <hip/hip_runtime.h>
#include <stdint.h>
#include <math.h>

// Disable implicit FP contraction globally: numpy never fuses a*a + s into
// fma. Explicit __builtin_fmaf below still emits v_fmac_f32 where we WANT fma
// (BLAS-style dot chain, single-rounded distance combine).
#pragma clang fp contract(off)

// Problem constants
#define B_   64
#define C_   64
#define HW_  1024
#define K_   512
#define N_   65536   // B_*HW_

// Output layout (float element offsets into d_out, reference return order)
#define OUT_Q    0ull                  // [B,C,H,W]  4194304
#define OUT_LOSS 4194304ull            // [B]        64
#define OUT_PERP 4194368ull            // scalar     1
#define OUT_ENC  4194369ull            // [N,K]      33554432
#define OUT_IDX  37748801ull           // [B,HW]     65536
#define OUT_DIST 37814337ull           // [N,K]      33554432

// Workspace layout (bytes)
#define WS_WT     0ull        // float[64*512]  transposed weight [c][k]
#define WS_WNORM  131072ull   // float[512]
#define WS_HIST   133120ull   // int[512]
#define WS_SUMSQ  135168ull   // float[64]
#define WS_ZERO_BYTES (512*4 + 64*4)

typedef float f32x4 __attribute__((ext_vector_type(4)));

static __device__ __forceinline__ void nt_store4(float* p, float a, float b,
                                                 float c, float d) {
  f32x4 v = {a, b, c, d};
  __builtin_nontemporal_store(v, (f32x4*)p);
}

// ---------------------------------------------------------------------------
// Prep: wt[c*512+k] = w[k*64+c]; wnorm[k] = numpy-pairwise sum of w[k,:]^2
// numpy pairwise for n=64: r[j] = sum_i a[8i+j] (sequential), then
// ((r0+r1)+(r2+r3))+((r4+r5)+(r6+r7))
// ---------------------------------------------------------------------------
__global__ __launch_bounds__(256) void vq_prep(const float* __restrict__ w,
                                               float* __restrict__ wt,
                                               float* __restrict__ wnorm) {
  const int t = threadIdx.x;
  const int g = blockIdx.x * 256 + t;          // 0..32767
  const int c = g >> 9;
  const int k = g & 511;
  wt[g] = w[k * 64 + c];

  if (blockIdx.x < 16) {                       // 4096 threads = 512 rows x 8
    const int row = g >> 3;
    const int j = g & 7;
    float s = 0.f;
    for (int i = 0; i < 8; ++i) {
      float v = w[row * 64 + 8 * i + j];
      float sq = v * v;                        // rounded square (no fma fuse)
      s = s + sq;
    }
    float o1 = __shfl_xor(s, 1); s = s + o1;   // (r0+r1) etc.
    float o2 = __shfl_xor(s, 2); s = s + o2;   // ((r0+r1)+(r2+r3))
    float o4 = __shfl_xor(s, 4); s = s + o4;   // full numpy tree
    if (j == 0) wnorm[row] = s;
  }
}

// ---------------------------------------------------------------------------
// Main: one block = 32 rows (same batch b, consecutive hw).
// wave w owns rows 8w..8w+7; lane l owns k in {4l..4l+3} u {256+4l..256+4l+3}
// (contiguous per lane -> dwordx4 everywhere: w loads, dist/enc stores).
// w is read straight from L2 (wt = 128 KB, cache-resident) with a 1-deep
// software prefetch -> no w_s LDS, no K-loop barriers, 4 blocks/CU.
// ---------------------------------------------------------------------------
__global__ __launch_bounds__(256, 4) void vq_main(const float* __restrict__ x,
                                                  const float* __restrict__ wt,
                                                  const float* __restrict__ wnorm,
                                                  float* __restrict__ out,
                                                  int* __restrict__ hist,
                                                  float* __restrict__ sumsq) {
  __shared__ float x_s[64 * 32];    // [c][m]
  __shared__ float an_s[32];
  __shared__ int   kmin_s[32];
  __shared__ float red_s[4];

  const int t   = threadIdx.x;
  const int blk = blockIdx.x;       // 0..2047
  const int n0  = blk * 32;
  const int b   = n0 >> 10;
  const int hw0 = n0 & 1023;
  const int wid = t >> 6;           // wave 0..3
  const int l   = t & 63;

  // ---- stage x tile: x_s[c][m] = x[b, c, hw0+m], 2x float4 per thread ----
  {
    const float* xb = x + (size_t)b * 65536 + hw0;
    const int c0 = t >> 3;          // 0..31
    const int m4 = (t & 7) * 4;
#pragma unroll
    for (int i = 0; i < 2; ++i) {
      int c = i * 32 + c0;
      float4 v = *(const float4*)(xb + (size_t)c * 1024 + m4);
      *(float4*)(&x_s[c * 32 + m4]) = v;
    }
  }
  __syncthreads();

  // ---- a_n = ||x_row||^2 with exact numpy pairwise tree (8 lanes/row).
  // Rows 8wid..8wid+7 are produced by wave wid itself -> no barrier needed
  // before the (same-wave) reads in the epilogue.
  {
    const int r = t >> 3, j = t & 7;
    float s = 0.f;
#pragma unroll
    for (int i = 0; i < 8; ++i) {
      float v = x_s[(8 * i + j) * 32 + r];
      float sq = v * v;
      s = s + sq;
    }
    float o1 = __shfl_xor(s, 1); s = s + o1;
    float o2 = __shfl_xor(s, 2); s = s + o2;
    float o4 = __shfl_xor(s, 4); s = s + o4;
    if (j == 0) an_s[r] = s;
  }

  // ---- wn for this lane's 8 k's (contiguous -> two dwordx4 from L2) ----
  float wn[8];
  *(float4*)(wn)     = *(const float4*)(wnorm + 4 * l);
  *(float4*)(wn + 4) = *(const float4*)(wnorm + 256 + 4 * l);

  // ---- dot products: acc[i][j] = x_row(8*wid+i) . w_col(k(l,j)) ----
  // Sequential fma chain over c=0..63 ascending (identical order to before).
  float acc[8][8];
#pragma unroll
  for (int i = 0; i < 8; ++i)
#pragma unroll
    for (int j = 0; j < 8; ++j) acc[i][j] = 0.f;

  const float* const wl = wt + 4 * l;        // lane's k-base in c-plane 0
  const float* const xw = x_s + 8 * wid;     // wave's row base
  float4 w0 = *(const float4*)(wl);          // c = 0
  float4 w1 = *(const float4*)(wl + 256);
#pragma unroll 2
  for (int c = 0; c < 64; ++c) {
    const int cn = (c + 1) & 63;             // wrap: last prefetch is dead
    const float4 nw0 = *(const float4*)(wl + cn * 512);        // 1-deep
    const float4 nw1 = *(const float4*)(wl + cn * 512 + 256);  // prefetch
    float xv[8];
    *(float4*)(xv)     = *(const float4*)(xw + c * 32);        // broadcast
    *(float4*)(xv + 4) = *(const float4*)(xw + c * 32 + 4);    // broadcast
    const float wv0[4] = {w0.x, w0.y, w0.z, w0.w};
    const float wv1[4] = {w1.x, w1.y, w1.z, w1.w};
#pragma unroll
    for (int i = 0; i < 8; ++i) {
#pragma unroll
      for (int j = 0; j < 4; ++j) {
        acc[i][j]     = __builtin_fmaf(xv[i], wv0[j], acc[i][j]);
        acc[i][j + 4] = __builtin_fmaf(xv[i], wv1[j], acc[i][j + 4]);
      }
    }
    w0 = nw0; w1 = nw1;
  }

  // ---- distances in place + lane-local argmin (first-occurrence) ----
  const int m_base = 8 * wid;
  float vb[8]; int kb[8];
#pragma unroll
  for (int i = 0; i < 8; ++i) {
    const float an = an_s[m_base + i];
#pragma unroll
    for (int j = 0; j < 8; ++j) {
      float tt = an + wn[j];                          // fl(a+b), numpy order
      acc[i][j] = __builtin_fmaf(-2.f, acc[i][j], tt); // fl(t - 2*dot)
    }
    float v = acc[i][0]; int k = 4 * l;               // j ascending == k asc.
#pragma unroll
    for (int j = 1; j < 8; ++j) {
      const int kj = ((j >> 2) << 8) + 4 * l + (j & 3);
      if (acc[i][j] < v) { v = acc[i][j]; k = kj; }
    }
    vb[i] = v; kb[i] = k;
  }

  // ---- 8 row-reductions, interleaved per butterfly step (latency pipelines;
  // ties -> lowest k = numpy first-index) ----
#pragma unroll
  for (int d = 1; d < 64; d <<= 1) {
#pragma unroll
    for (int i = 0; i < 8; ++i) {
      float v2 = __shfl_xor(vb[i], d);
      int   k2 = __shfl_xor(kb[i], d);
      if (v2 < vb[i] || (v2 == vb[i] && k2 < kb[i])) { vb[i] = v2; kb[i] = k2; }
    }
  }

  // ---- vectorized nontemporal stores: dist + one-hot enc, idx, hist ----
  float* const dist_o = out + OUT_DIST;
  float* const enc_o  = out + OUT_ENC;
#pragma unroll
  for (int i = 0; i < 8; ++i) {
    const int m = m_base + i;
    const size_t n = (size_t)(n0 + m);
    float* dr = dist_o + n * 512;
    float* er = enc_o  + n * 512;
    nt_store4(dr + 4 * l,       acc[i][0], acc[i][1], acc[i][2], acc[i][3]);
    nt_store4(dr + 256 + 4 * l, acc[i][4], acc[i][5], acc[i][6], acc[i][7]);
    const int kbi = kb[i];
    const int k0 = 4 * l;
    nt_store4(er + 4 * l,
              (k0 + 0 == kbi) ? 1.f : 0.f, (k0 + 1 == kbi) ? 1.f : 0.f,
              (k0 + 2 == kbi) ? 1.f : 0.f, (k0 + 3 == kbi) ? 1.f : 0.f);
    nt_store4(er + 256 + 4 * l,
              (k0 + 256 == kbi) ? 1.f : 0.f, (k0 + 257 == kbi) ? 1.f : 0.f,
              (k0 + 258 == kbi) ? 1.f : 0.f, (k0 + 259 == kbi) ? 1.f : 0.f);
    if (l == i) {
      out[OUT_IDX + n] = (float)kbi;
      atomicAdd(&hist[kbi], 1);
      kmin_s[m] = kbi;
    }
  }
  __syncthreads();   // kmin_s visible to all waves

  // ---- q_out (NCHW, float4) + per-batch loss partial ----
  float lsum = 0.f;
  float* const q_o = out + OUT_Q;
#pragma unroll
  for (int it = 0; it < 2; ++it) {
    const int c  = it * 32 + (t >> 3);
    const int m4 = (t & 7) * 4;
    float xq[4];
    *(float4*)(xq) = *(const float4*)(&x_s[c * 32 + m4]);
    float qv[4];
#pragma unroll
    for (int u = 0; u < 4; ++u) {
      const int kbm = kmin_s[m4 + u];
      qv[u] = wt[(size_t)c * 512 + kbm];     // L1/L2-cached gather
      const float d = qv[u] - xq[u];
      lsum = __builtin_fmaf(d, d, lsum);
    }
    nt_store4(&q_o[(size_t)b * 65536 + (size_t)c * 1024 + hw0 + m4],
              qv[0], qv[1], qv[2], qv[3]);   // coalesced dwordx4
  }
#pragma unroll
  for (int d = 1; d < 64; d <<= 1) lsum += __shfl_xor(lsum, d);
  if (l == 0) red_s[wid] = lsum;
  __syncthreads();
  if (t == 0) {
    float s = (red_s[0] + red_s[1]) + (red_s[2] + red_s[3]);
    atomicAdd(sumsq + b, s);
  }
}

// ---------------------------------------------------------------------------
// Finalize: perplexity from histogram; loss[b] = 1.25 * sumsq[b]/65536
// ---------------------------------------------------------------------------
__global__ __launch_bounds__(512) void vq_fin(const int* __restrict__ hist,
                                              const float* __restrict__ sumsq,
                                              float* __restrict__ out) {
  __shared__ double red[8];
  const int t = threadIdx.x;
  double p = (double)hist[t] * (1.0 / 65536.0);
  double term = p * log(p + 1e-10);
  for (int d = 1; d < 64; d <<= 1) term += __shfl_xor(term, d);
  if ((t & 63) == 0) red[t >> 6] = term;
  __syncthreads();
  if (t == 0) {
    double s = 0.0;
    for (int i = 0; i < 8; ++i) s += red[i];
    out[OUT_PERP] = (float)exp(-s);
  }
  if (t < 64) {
    float m = sumsq[t] * (1.0f / 65536.0f);   // exact /2^16
    out[OUT_LOSS + t] = m + 0.25f * m;        // fl(m + fl(0.25m)), numpy order
  }
}

// ---------------------------------------------------------------------------
extern "C" void kernel_launch(void* const* d_in, const int* in_sizes, int n_in,
                              void* d_out, int out_size, void* d_ws, size_t ws_size,
                              hipStream_t stream) {
  const float* x = (const float*)d_in[0];   // [B,C,H,W] fp32
  const float* w = (const float*)d_in[1];   // [K,C] fp32
  float* out = (float*)d_out;
  char* ws = (char*)d_ws;
  float* wt    = (float*)(ws + WS_WT);
  float* wnorm = (float*)(ws + WS_WNORM);
  int*   hist  = (int*)  (ws + WS_HIST);
  float* sumsq = (float*)(ws + WS_SUMSQ);

  (void)hipMemsetAsync(ws + WS_HIST, 0, WS_ZERO_BYTES, stream);
  vq_prep<<<128, 256, 0, stream>>>(w, wt, wnorm);
  vq_main<<<2048, 256, 0, stream>>>(x, wt, wnorm, out, hist, sumsq);
  vq_fin<<<1, 512, 0, stream>>>(hist, sumsq, out);
}